// Round 7
// baseline (28671.948 us; speedup 1.0000x reference)
//
#include <hip/hip_runtime.h>
#include <math.h>

#define BATCH 256
#define TT    784
#define HH    512
#define NCLS  10
#define NT    1024     // 16 waves: wave w owns k-window [32w, 32w+32)

// One block per batch row. W_hh (1 MB) fully register-resident per block:
// 1024 threads x 256 floats (64 named float4). Zero inter-block traffic --
// the whole 784-step recurrence runs out of LDS + registers.
// Thread map: lane l = tid&63 owns cols [8l, 8l+8); wave w = tid>>6 owns
// k in [32w, 32w+32). h reads are wave-uniform LDS broadcasts.

__global__ __launch_bounds__(NT, 4) void rnn_row_kernel(
    const float* __restrict__ inputs, const int* __restrict__ order,
    const float* __restrict__ W_ih, const float* __restrict__ b_ih,
    const float* __restrict__ W_hh, const float* __restrict__ b_hh,
    float* __restrict__ hout)
{
    __shared__ float hcur[HH];           // 2 KB  : h_t
    __shared__ float pbuf[16 * HH];      // 32 KB : partials [kg][col]
    __shared__ float xrow[TT];           // 3.1 KB: x[b][order[t]]

    const int tid  = threadIdx.x;
    const int b    = blockIdx.x;         // batch row
    const int w    = tid >> 6;           // k-group 0..15
    const int l    = tid & 63;           // lane: cols [8l, 8l+8)
    const int colb = l * 8;

    // ---- W_hh slice in NAMED registers: 8 cols x 32 k = 64 float4 (256 VGPR)
#define LOADW(C) \
    const float4* ws##C = (const float4*)(W_hh + (size_t)(colb + C) * HH + w * 32); \
    const float4 w##C##0 = ws##C[0], w##C##1 = ws##C[1], w##C##2 = ws##C[2], w##C##3 = ws##C[3], \
                 w##C##4 = ws##C[4], w##C##5 = ws##C[5], w##C##6 = ws##C[6], w##C##7 = ws##C[7];
    LOADW(0) LOADW(1) LOADW(2) LOADW(3) LOADW(4) LOADW(5) LOADW(6) LOADW(7)
#undef LOADW

    // ---- reducer-thread constants (tid<128): col-quad q = tid, cols 4q..4q+3
    float4 wihR = make_float4(0.f, 0.f, 0.f, 0.f);
    float4 biasR = wihR;
    if (tid < 128) {
        wihR = ((const float4*)W_ih)[tid];
        const float4 bi = ((const float4*)b_ih)[tid];
        const float4 bh = ((const float4*)b_hh)[tid];
        biasR = make_float4(bi.x + bh.x, bi.y + bh.y, bi.z + bh.z, bi.w + bh.w);
    }

    // ---- init h=0, pre-gather x
    if (tid < 128) ((float4*)hcur)[tid] = make_float4(0.f, 0.f, 0.f, 0.f);
    if (tid < TT)  xrow[tid] = inputs[(size_t)b * TT + order[tid]];
    __syncthreads();

    const float4* h4w = (const float4*)hcur + w * 8;   // this wave's k-window
    float4* pb4 = (float4*)pbuf;

    for (int t = 0; t < TT; ++t) {
        // ---- partials: 8 broadcast h reads, 256 FMAs into 8 named accs
        const float4 hv0 = h4w[0], hv1 = h4w[1], hv2 = h4w[2], hv3 = h4w[3];
        const float4 hv4 = h4w[4], hv5 = h4w[5], hv6 = h4w[6], hv7 = h4w[7];
        float a0 = 0.f, a1 = 0.f, a2 = 0.f, a3 = 0.f, a4 = 0.f, a5 = 0.f, a6 = 0.f, a7 = 0.f;

#define FMA4(ACC, WV, HV) \
        ACC = fmaf(WV.x, HV.x, ACC); ACC = fmaf(WV.y, HV.y, ACC); \
        ACC = fmaf(WV.z, HV.z, ACC); ACC = fmaf(WV.w, HV.w, ACC);
#define COL(C) \
        FMA4(a##C, w##C##0, hv0) FMA4(a##C, w##C##1, hv1) \
        FMA4(a##C, w##C##2, hv2) FMA4(a##C, w##C##3, hv3) \
        FMA4(a##C, w##C##4, hv4) FMA4(a##C, w##C##5, hv5) \
        FMA4(a##C, w##C##6, hv6) FMA4(a##C, w##C##7, hv7)
        COL(0) COL(1) COL(2) COL(3) COL(4) COL(5) COL(6) COL(7)
#undef COL
#undef FMA4

        // pbuf[w][colb..colb+8) as two b128
        pb4[w * 128 + l * 2 + 0] = make_float4(a0, a1, a2, a3);
        pb4[w * 128 + l * 2 + 1] = make_float4(a4, a5, a6, a7);
        __syncthreads();                 // partials ready

        // ---- reduce 16 k-groups (2 waves), tanh, write h_{t+1}
        if (tid < 128) {
            float4 s = pb4[tid];
            #pragma unroll
            for (int g = 1; g < 16; ++g) {
                const float4 v = pb4[g * 128 + tid];
                s.x += v.x; s.y += v.y; s.z += v.z; s.w += v.w;
            }
            const float xv = xrow[t];
            s.x = tanhf(s.x + xv * wihR.x + biasR.x);
            s.y = tanhf(s.y + xv * wihR.y + biasR.y);
            s.z = tanhf(s.z + xv * wihR.z + biasR.z);
            s.w = tanhf(s.w + xv * wihR.w + biasR.w);
            ((float4*)hcur)[tid] = s;
        }
        __syncthreads();                 // h_{t+1} visible; pbuf WAR safe
    }

    // ---- export final h for the tail kernel
    if (tid < 128) ((float4*)hout)[(size_t)b * 128 + tid] = ((const float4*)hcur)[tid];
}

__global__ __launch_bounds__(256) void rnn_tail_kernel(
    const float* __restrict__ hfin,
    const float* __restrict__ lin_W, const float* __restrict__ lin_b,
    const int* __restrict__ y, float* __restrict__ out)
{
    __shared__ float redf[256];
    __shared__ int   redi[256];
    const int b = threadIdx.x;
    const float* hrow = hfin + (size_t)b * HH;

    float logits[NCLS];
    #pragma unroll
    for (int c = 0; c < NCLS; ++c) {
        float s = lin_b[c];
        const float* wrow = lin_W + (size_t)c * HH;
        for (int k = 0; k < HH; k += 4) {
            float4 hv = *(const float4*)(hrow + k);
            float4 wv = *(const float4*)(wrow + k);
            s += hv.x * wv.x + hv.y * wv.y + hv.z * wv.z + hv.w * wv.w;
        }
        logits[c] = s;
    }
    int am = 0; float m = logits[0];
    #pragma unroll
    for (int c = 1; c < NCLS; ++c) if (logits[c] > m) { m = logits[c]; am = c; } // first-max = jnp.argmax
    float sum = 0.0f;
    #pragma unroll
    for (int c = 0; c < NCLS; ++c) sum += expf(logits[c] - m);
    const float lse = m + logf(sum);
    const int yy = y[b];
    redf[b] = lse - logits[yy];           // -logp[b, y[b]]
    redi[b] = (am == yy) ? 1 : 0;
    __syncthreads();
    for (int s2 = 128; s2 > 0; s2 >>= 1) {
        if (b < s2) { redf[b] += redf[b + s2]; redi[b] += redi[b + s2]; }
        __syncthreads();
    }
    if (b == 0) {
        out[0] = redf[0] / (float)BATCH;  // loss
        out[1] = (float)redi[0];          // correct count
    }
}

extern "C" void kernel_launch(void* const* d_in, const int* in_sizes, int n_in,
                              void* d_out, int out_size, void* d_ws, size_t ws_size,
                              hipStream_t stream) {
    const float* inputs = (const float*)d_in[0];
    const int*   y      = (const int*)  d_in[1];
    const int*   order  = (const int*)  d_in[2];
    const float* W_ih   = (const float*)d_in[3];
    const float* b_ih   = (const float*)d_in[4];
    const float* W_hh   = (const float*)d_in[5];
    const float* b_hh   = (const float*)d_in[6];
    const float* lin_W  = (const float*)d_in[7];
    const float* lin_b  = (const float*)d_in[8];
    float* out = (float*)d_out;

    float* hout = (float*)d_ws;          // 512 KB: final h (fully rewritten every call)

    hipLaunchKernelGGL(rnn_row_kernel, dim3(BATCH), dim3(NT), 0, stream,
                       inputs, order, W_ih, b_ih, W_hh, b_hh, hout);

    hipLaunchKernelGGL(rnn_tail_kernel, dim3(1), dim3(256), 0, stream,
                       hout, lin_W, lin_b, y, out);
}

// Round 8
// 3248.181 us; speedup vs baseline: 8.8271x; 8.8271x over previous
//
#include <hip/hip_runtime.h>
#include <math.h>

#define BATCH 256
#define TT    784
#define HH    512
#define NCLS  10

#define NB 32          // batch groups
#define NJ 8           // j groups (blocks per group) == waves per block
#define MB 8           // batch rows per group   (BATCH/NB)
#define HJ 64          // output cols per block  (HH/NJ)
#define NT 512         // threads per block (8 waves)

typedef unsigned long long ull;
typedef unsigned int uint32;

#define AL(p)    __hip_atomic_load((p), __ATOMIC_RELAXED, __HIP_MEMORY_SCOPE_AGENT)
#define AS(p, v) __hip_atomic_store((p), (v), __ATOMIC_RELAXED, __HIP_MEMORY_SCOPE_AGENT)

// d_ws layout:
//   [0, 2048)   : flags ull[NB][8] — flag[bb][g]: two u32 halves, one per
//                 reducer wave of producer g. half >= t  <=>  that wave's
//                 h slice for step t is visible (sc1-stored + vmcnt-drained).
//   [8192, ...) : double-buffered h state (2 * B * H floats, plain f32,
//                 always accessed with sc1 relaxed atomics).
//
// Exchange is per-WAVE: wave w's k-window [64w,64w+64) == producer w's col
// slice, so each wave gates only on its one producer and computes as soon
// as that 2 KB slice arrives. No block-wide gate before compute; no
// acquire/release cache maintenance anywhere.

__global__ __launch_bounds__(256) void rnn_init_kernel(ull* flags) {
    const int i = blockIdx.x * blockDim.x + threadIdx.x;
    if (i < NB * NJ) AS(&flags[i], 0ULL);
}

__global__ __launch_bounds__(NT, 2) void rnn_main_kernel(
    const float* __restrict__ inputs, const int* __restrict__ order,
    const float* __restrict__ W_ih, const float* __restrict__ b_ih,
    const float* __restrict__ W_hh, const float* __restrict__ b_hh,
    float* __restrict__ hbuf, ull* __restrict__ flags)
{
    __shared__ float hp[MB * HH];            // 16 KB: h tile (global col layout)
    __shared__ float pbuf[32 * MB * HJ];     // 64 KB: partials [kg][b][j*4+cg]
    __shared__ float xall[TT * MB];          // 25 KB: pre-gathered inputs[b][order[t]]
    __shared__ float wih_s[HJ];
    __shared__ float bias_s[HJ];

    const int tid   = threadIdx.x;
    const int blk   = blockIdx.x;
    const int bb    = blk & (NB - 1);
    const int jjg   = blk >> 5;         // this block produces cols [jjg*64, +64)
    const int jbase = jjg * HJ;
    const int bbase = bb * MB;
    const int j   = tid & 15;           // compute map: base column lane
    const int kg  = tid >> 4;           // k-chunk 0..31 (16 k each)
    const int kg4 = kg * 4;
    const int w   = tid >> 6;           // wave index == this wave's one producer
    const int l   = tid & 63;
    const int r   = l >> 3;             // staging map: batch row 0..7
    const int c8  = l & 7;              // staging map: 8-float chunk in the 64-col slice
    const int colbase = w * 64 + c8 * 8;

    // ---- W_hh slice in NAMED registers: 4 cols x 16 k = 16 float4
    const float4* wp0 = (const float4*)(W_hh + (size_t)(jbase + j +  0) * HH + kg * 16);
    const float4* wp1 = (const float4*)(W_hh + (size_t)(jbase + j + 16) * HH + kg * 16);
    const float4* wp2 = (const float4*)(W_hh + (size_t)(jbase + j + 32) * HH + kg * 16);
    const float4* wp3 = (const float4*)(W_hh + (size_t)(jbase + j + 48) * HH + kg * 16);
    const float4 wa0 = wp0[0], wa1 = wp0[1], wa2 = wp0[2], wa3 = wp0[3];
    const float4 wb0 = wp1[0], wb1 = wp1[1], wb2 = wp1[2], wb3 = wp1[3];
    const float4 wc0 = wp2[0], wc1 = wp2[1], wc2 = wp2[2], wc3 = wp2[3];
    const float4 wd0 = wp3[0], wd1 = wp3[1], wd2 = wp3[2], wd3 = wp3[3];

    if (tid < HJ) {
        wih_s[tid]  = W_ih[jbase + tid];
        bias_s[tid] = b_ih[jbase + tid] + b_hh[jbase + tid];
    }
    for (int idx = tid; idx < TT * MB; idx += NT) {
        const int t = idx >> 3;
        const int b = idx & (MB - 1);
        xall[idx] = inputs[(size_t)(bbase + b) * TT + order[t]];
    }
    // h_0 = 0: zero hp directly (no global h init needed)
    ((float4*)hp)[tid]      = make_float4(0.f, 0.f, 0.f, 0.f);
    ((float4*)hp)[tid + NT] = make_float4(0.f, 0.f, 0.f, 0.f);
    __syncthreads();

    const float4* hp4 = (const float4*)hp;
    float4* P4 = (float4*)pbuf;
    const ull* fp = &flags[bb * NJ + w];

    for (int t = 0; t < TT; ++t) {
        const int p = t & 1;

        // ---- per-wave gate + stage: poll ONE flag-pair, load ONE 2 KB slice
        if (t > 0 && w != jjg) {
            const uint32 tg = (uint32)t;
            ull f = AL(fp);
            while ((uint32)f < tg || (uint32)(f >> 32) < tg) f = AL(fp);
            const ull* src = (const ull*)(hbuf + (size_t)p * BATCH * HH
                                          + (size_t)(bbase + r) * HH + colbase);
            const ull u0 = AL(src + 0), u1 = AL(src + 1);
            const ull u2 = AL(src + 2), u3 = AL(src + 3);
            ull* hpu = (ull*)hp;
            const int di = (r * HH + colbase) >> 1;
            hpu[di + 0] = u0; hpu[di + 1] = u1; hpu[di + 2] = u2; hpu[di + 3] = u3;
        }
        // intra-wave LDS RAW: compiler's lgkmcnt covers the hp reads below. No barrier.

        // ---- partial dot products: this wave reads ONLY hp cols [64w, 64w+64)
        float a00=0.f,a01=0.f,a02=0.f,a03=0.f,a04=0.f,a05=0.f,a06=0.f,a07=0.f;
        float a10=0.f,a11=0.f,a12=0.f,a13=0.f,a14=0.f,a15=0.f,a16=0.f,a17=0.f;
        float a20=0.f,a21=0.f,a22=0.f,a23=0.f,a24=0.f,a25=0.f,a26=0.f,a27=0.f;
        float a30=0.f,a31=0.f,a32=0.f,a33=0.f,a34=0.f,a35=0.f,a36=0.f,a37=0.f;

#define FMA4(ACC, WV, HV) \
        ACC = fmaf(WV.x, HV.x, ACC); ACC = fmaf(WV.y, HV.y, ACC); \
        ACC = fmaf(WV.z, HV.z, ACC); ACC = fmaf(WV.w, HV.w, ACC);
#define ROW(B) { \
        const float4* hr = hp4 + (B)*128 + kg4; \
        const float4 h0 = hr[0], h1 = hr[1], h2 = hr[2], h3 = hr[3]; \
        FMA4(a0##B, wa0, h0) FMA4(a0##B, wa1, h1) FMA4(a0##B, wa2, h2) FMA4(a0##B, wa3, h3) \
        FMA4(a1##B, wb0, h0) FMA4(a1##B, wb1, h1) FMA4(a1##B, wb2, h2) FMA4(a1##B, wb3, h3) \
        FMA4(a2##B, wc0, h0) FMA4(a2##B, wc1, h1) FMA4(a2##B, wc2, h2) FMA4(a2##B, wc3, h3) \
        FMA4(a3##B, wd0, h0) FMA4(a3##B, wd1, h1) FMA4(a3##B, wd2, h2) FMA4(a3##B, wd3, h3) }

        ROW(0) ROW(1) ROW(2) ROW(3) ROW(4) ROW(5) ROW(6) ROW(7)
#undef ROW
#undef FMA4

        {
            float4* dst = P4 + (size_t)kg * 128 + j;
            dst[0*16] = make_float4(a00, a10, a20, a30);
            dst[1*16] = make_float4(a01, a11, a21, a31);
            dst[2*16] = make_float4(a02, a12, a22, a32);
            dst[3*16] = make_float4(a03, a13, a23, a33);
            dst[4*16] = make_float4(a04, a14, a24, a34);
            dst[5*16] = make_float4(a05, a15, a25, a35);
            dst[6*16] = make_float4(a06, a16, a26, a36);
            dst[7*16] = make_float4(a07, a17, a27, a37);
        }
        __syncthreads();                 // B: all partials ready

        // ---- reduce (2 waves), tanh, publish: sc1 stores + own-drain + flag half
        if (tid < 128) {
            const int rb = tid >> 4;
            const int rj = tid & 15;
            float4 s = P4[rb * 16 + rj];
            #pragma unroll
            for (int g = 1; g < 32; ++g) {
                const float4 v = P4[(size_t)g * 128 + rb * 16 + rj];
                s.x += v.x; s.y += v.y; s.z += v.z; s.w += v.w;
            }
            const float xv = xall[t * MB + rb];
            const float h0 = tanhf(s.x + xv * wih_s[rj +  0] + bias_s[rj +  0]);
            const float h1 = tanhf(s.y + xv * wih_s[rj + 16] + bias_s[rj + 16]);
            const float h2 = tanhf(s.z + xv * wih_s[rj + 32] + bias_s[rj + 32]);
            const float h3 = tanhf(s.w + xv * wih_s[rj + 48] + bias_s[rj + 48]);
            float* drow = hbuf + (size_t)(p ^ 1) * BATCH * HH + (size_t)(bbase + rb) * HH + jbase;
            AS(&drow[rj +  0], h0);
            AS(&drow[rj + 16], h1);
            AS(&drow[rj + 32], h2);
            AS(&drow[rj + 48], h3);
            // own-slice shortcut for wave jjg next step
            hp[rb * HH + jbase + rj +  0] = h0;
            hp[rb * HH + jbase + rj + 16] = h1;
            hp[rb * HH + jbase + rj + 32] = h2;
            hp[rb * HH + jbase + rj + 48] = h3;
            // drain THIS wave's 4 sc1 stores, then publish this wave's flag half
            asm volatile("s_waitcnt vmcnt(0)" ::: "memory");
            if ((tid & 63) == 0) {
                uint32* half = ((uint32*)&flags[bb * NJ + jjg]) + (tid >> 6);
                AS(half, (uint32)(t + 1));
            }
        }
        __syncthreads();                 // C: pbuf WAR + own-slice visible to wave jjg
    }
}

__global__ __launch_bounds__(256) void rnn_tail_kernel(
    const float* __restrict__ hfin,   // final h in buf 0 (TT even)
    const float* __restrict__ lin_W, const float* __restrict__ lin_b,
    const int* __restrict__ y, float* __restrict__ out)
{
    __shared__ float redf[256];
    __shared__ int   redi[256];
    const int b = threadIdx.x;
    const float* hrow = hfin + (size_t)b * HH;

    float logits[NCLS];
    #pragma unroll
    for (int c = 0; c < NCLS; ++c) {
        float s = lin_b[c];
        const float* wrow = lin_W + (size_t)c * HH;
        for (int k = 0; k < HH; k += 4) {
            float4 hv = *(const float4*)(hrow + k);
            float4 wv = *(const float4*)(wrow + k);
            s += hv.x * wv.x + hv.y * wv.y + hv.z * wv.z + hv.w * wv.w;
        }
        logits[c] = s;
    }
    int am = 0; float m = logits[0];
    #pragma unroll
    for (int c = 1; c < NCLS; ++c) if (logits[c] > m) { m = logits[c]; am = c; } // first-max = jnp.argmax
    float sum = 0.0f;
    #pragma unroll
    for (int c = 0; c < NCLS; ++c) sum += expf(logits[c] - m);
    const float lse = m + logf(sum);
    const int yy = y[b];
    redf[b] = lse - logits[yy];           // -logp[b, y[b]]
    redi[b] = (am == yy) ? 1 : 0;
    __syncthreads();
    for (int s2 = 128; s2 > 0; s2 >>= 1) {
        if (b < s2) { redf[b] += redf[b + s2]; redi[b] += redi[b + s2]; }
        __syncthreads();
    }
    if (b == 0) {
        out[0] = redf[0] / (float)BATCH;  // loss
        out[1] = (float)redi[0];          // correct count
    }
}

extern "C" void kernel_launch(void* const* d_in, const int* in_sizes, int n_in,
                              void* d_out, int out_size, void* d_ws, size_t ws_size,
                              hipStream_t stream) {
    const float* inputs = (const float*)d_in[0];
    const int*   y      = (const int*)  d_in[1];
    const int*   order  = (const int*)  d_in[2];
    const float* W_ih   = (const float*)d_in[3];
    const float* b_ih   = (const float*)d_in[4];
    const float* W_hh   = (const float*)d_in[5];
    const float* b_hh   = (const float*)d_in[6];
    const float* lin_W  = (const float*)d_in[7];
    const float* lin_b  = (const float*)d_in[8];
    float* out = (float*)d_out;

    ull*   flags = (ull*)d_ws;
    float* hbuf  = (float*)((char*)d_ws + 8192);

    hipLaunchKernelGGL(rnn_init_kernel, dim3(1), dim3(256), 0, stream, flags);

    void* args[] = {(void*)&inputs, (void*)&order, (void*)&W_ih, (void*)&b_ih,
                    (void*)&W_hh, (void*)&b_hh, (void*)&hbuf, (void*)&flags};
    hipError_t err = hipLaunchCooperativeKernel((void*)rnn_main_kernel,
                                                dim3(NB * NJ), dim3(NT), args, 0, stream);
    if (err != hipSuccess) {
        hipLaunchKernelGGL(rnn_main_kernel, dim3(NB * NJ), dim3(NT), 0, stream,
                           inputs, order, W_ih, b_ih, W_hh, b_hh, hbuf, flags);
    }

    hipLaunchKernelGGL(rnn_tail_kernel, dim3(1), dim3(256), 0, stream,
                       hbuf, lin_W, lin_b, y, out);
}

// Round 9
// 3245.650 us; speedup vs baseline: 8.8340x; 1.0008x over previous
//
#include <hip/hip_runtime.h>
#include <math.h>

#define BATCH 256
#define TT    784
#define HH    512
#define NCLS  10

#define NB 64          // batch groups
#define NJ 4           // blocks per group; block owns 128 cols
#define MB 4           // batch rows per group
#define HJ 128         // output cols per block
#define NT 512         // threads per block (8 waves)

typedef unsigned long long ull;
typedef unsigned int uint32;

#define AL(p)    __hip_atomic_load((p), __ATOMIC_RELAXED, __HIP_MEMORY_SCOPE_AGENT)
#define AS(p, v) __hip_atomic_store((p), (v), __ATOMIC_RELAXED, __HIP_MEMORY_SCOPE_AGENT)

// d_ws layout:
//   [0, 4096)   : wflags uint32[NB][16] — flag[bb][g*4+r] >= t  <=>  producer g's
//                 row r of h_t is visible (sc1-stored + that wave's vmcnt drained).
//                 One 64 B line per group.
//   [8192, ...) : double-buffered h state (2 * B * H f32, accessed sc1 relaxed).
//
// Per-WAVE exchange: wave w's k-window [64w,64w+64) lies inside producer
// g=w>>1's col slice [128g,+128), so each wave gates on one producer's 4
// row-flags and stages 1 KB. Per-row publish: reducer wave r stores row r
// contiguously, drains its own stores, bumps flag[jjg*4+r]. No cache
// maintenance anywhere (all relaxed agent-scope = sc0 sc1, L3-coherent).

__global__ __launch_bounds__(256) void rnn_init_kernel(uint32* wflags) {
    const int i = blockIdx.x * blockDim.x + threadIdx.x;
    if (i < NB * 16) AS(&wflags[i], 0u);
}

__global__ __launch_bounds__(NT, 2) void rnn_main_kernel(
    const float* __restrict__ inputs, const int* __restrict__ order,
    const float* __restrict__ W_ih, const float* __restrict__ b_ih,
    const float* __restrict__ W_hh, const float* __restrict__ b_hh,
    float* __restrict__ hbuf, uint32* __restrict__ wflags)
{
    __shared__ float hp[MB * HH];            // 8 KB : h tile (canonical col layout)
    __shared__ float pbuf[16 * MB * HJ];     // 32 KB: partials [kg][row][pack j]
    __shared__ float xall[TT * MB];          // 12.5 KB: inputs[b][order[t]]
    __shared__ float wih_s[HJ];
    __shared__ float bias_s[HJ];

    const int tid   = threadIdx.x;
    const int blk   = blockIdx.x;
    const int bb    = blk & (NB - 1);        // group; members blk=bb+64g -> same XCD under %8
    const int jjg   = blk >> 6;              // producer id 0..3: cols [jjg*128, +128)
    const int jbase = jjg * HJ;
    const int bbase = bb * MB;
    const int j   = tid & 31;                // base col lane: cols {j, j+32, j+64, j+96}
    const int kg  = tid >> 5;                // k-chunk 0..15 (32 k each)
    const int w   = tid >> 6;                // wave: k-window [64w,+64), producer g=w>>1
    const int g   = w >> 1;
    const int l   = tid & 63;
    const int r4  = l >> 4;                  // staging: batch row 0..3
    const int c4  = l & 15;                  // staging: 16B chunk within 64-col window

    // ---- W_hh slice in NAMED registers: 4 cols x 32 k = 32 float4 (128 VGPR)
    const float4* wpa = (const float4*)(W_hh + (size_t)(jbase + j +  0) * HH + kg * 32);
    const float4* wpb = (const float4*)(W_hh + (size_t)(jbase + j + 32) * HH + kg * 32);
    const float4* wpc = (const float4*)(W_hh + (size_t)(jbase + j + 64) * HH + kg * 32);
    const float4* wpd = (const float4*)(W_hh + (size_t)(jbase + j + 96) * HH + kg * 32);
    const float4 wa0 = wpa[0], wa1 = wpa[1], wa2 = wpa[2], wa3 = wpa[3];
    const float4 wa4 = wpa[4], wa5 = wpa[5], wa6 = wpa[6], wa7 = wpa[7];
    const float4 wb0 = wpb[0], wb1 = wpb[1], wb2 = wpb[2], wb3 = wpb[3];
    const float4 wb4 = wpb[4], wb5 = wpb[5], wb6 = wpb[6], wb7 = wpb[7];
    const float4 wc0 = wpc[0], wc1 = wpc[1], wc2 = wpc[2], wc3 = wpc[3];
    const float4 wc4 = wpc[4], wc5 = wpc[5], wc6 = wpc[6], wc7 = wpc[7];
    const float4 wd0 = wpd[0], wd1 = wpd[1], wd2 = wpd[2], wd3 = wpd[3];
    const float4 wd4 = wpd[4], wd5 = wpd[5], wd6 = wpd[6], wd7 = wpd[7];

    if (tid < HJ) {
        wih_s[tid]  = W_ih[jbase + tid];
        bias_s[tid] = b_ih[jbase + tid] + b_hh[jbase + tid];
    }
    for (int idx = tid; idx < TT * MB; idx += NT) {
        const int t = idx >> 2;
        const int b = idx & (MB - 1);
        xall[idx] = inputs[(size_t)(bbase + b) * TT + order[t]];
    }
    ((float4*)hp)[tid] = make_float4(0.f, 0.f, 0.f, 0.f);   // h_0 = 0 (8 KB)
    __syncthreads();

    const float4* hp4 = (const float4*)hp;
    float4* P4 = (float4*)pbuf;

    for (int t = 0; t < TT; ++t) {
        const int p = t & 1;

        // ---- per-wave gate + stage: poll producer g's 4 row-flags (one line),
        //      then load this wave's 1 KB slice
        if (t > 0 && g != jjg) {
            const uint32 tg = (uint32)t;
            const ull* f8 = (const ull*)(wflags + bb * 16 + g * 4);
            for (;;) {
                const ull f0 = AL(f8), f1 = AL(f8 + 1);
                if ((uint32)f0 >= tg && (uint32)(f0 >> 32) >= tg &&
                    (uint32)f1 >= tg && (uint32)(f1 >> 32) >= tg) break;
            }
            const ull* src = (const ull*)(hbuf + (size_t)p * BATCH * HH
                                          + (size_t)(bbase + r4) * HH + w * 64 + c4 * 4);
            const ull u0 = AL(src), u1 = AL(src + 1);
            ull* hpu = (ull*)hp;
            const int di = (r4 * HH + w * 64 + c4 * 4) >> 1;
            hpu[di] = u0; hpu[di + 1] = u1;
        }
        // intra-wave LDS RAW: compiler's lgkmcnt covers the hp reads below.

        // ---- partials: 4 rows x 4 cols, k-window 32; h reads are 2-addr broadcasts
        float aa0=0.f,aa1=0.f,aa2=0.f,aa3=0.f;
        float ab0=0.f,ab1=0.f,ab2=0.f,ab3=0.f;
        float ac0=0.f,ac1=0.f,ac2=0.f,ac3=0.f;
        float ad0=0.f,ad1=0.f,ad2=0.f,ad3=0.f;

#define FMA4(ACC, WV, HV) \
        ACC = fmaf(WV.x, HV.x, ACC); ACC = fmaf(WV.y, HV.y, ACC); \
        ACC = fmaf(WV.z, HV.z, ACC); ACC = fmaf(WV.w, HV.w, ACC);
#define ROW(B) { \
        const float4* hr = hp4 + (B)*128 + kg*8; \
        const float4 h0=hr[0],h1=hr[1],h2=hr[2],h3=hr[3]; \
        const float4 h4=hr[4],h5=hr[5],h6=hr[6],h7=hr[7]; \
        FMA4(aa##B, wa0,h0) FMA4(aa##B, wa1,h1) FMA4(aa##B, wa2,h2) FMA4(aa##B, wa3,h3) \
        FMA4(aa##B, wa4,h4) FMA4(aa##B, wa5,h5) FMA4(aa##B, wa6,h6) FMA4(aa##B, wa7,h7) \
        FMA4(ab##B, wb0,h0) FMA4(ab##B, wb1,h1) FMA4(ab##B, wb2,h2) FMA4(ab##B, wb3,h3) \
        FMA4(ab##B, wb4,h4) FMA4(ab##B, wb5,h5) FMA4(ab##B, wb6,h6) FMA4(ab##B, wb7,h7) \
        FMA4(ac##B, wc0,h0) FMA4(ac##B, wc1,h1) FMA4(ac##B, wc2,h2) FMA4(ac##B, wc3,h3) \
        FMA4(ac##B, wc4,h4) FMA4(ac##B, wc5,h5) FMA4(ac##B, wc6,h6) FMA4(ac##B, wc7,h7) \
        FMA4(ad##B, wd0,h0) FMA4(ad##B, wd1,h1) FMA4(ad##B, wd2,h2) FMA4(ad##B, wd3,h3) \
        FMA4(ad##B, wd4,h4) FMA4(ad##B, wd5,h5) FMA4(ad##B, wd6,h6) FMA4(ad##B, wd7,h7) }

        ROW(0) ROW(1) ROW(2) ROW(3)
#undef ROW
#undef FMA4

        // pack: P4[(kg*4+row)*32 + j] = cols {j, j+32, j+64, j+96}
        P4[(kg*4 + 0)*32 + j] = make_float4(aa0, ab0, ac0, ad0);
        P4[(kg*4 + 1)*32 + j] = make_float4(aa1, ab1, ac1, ad1);
        P4[(kg*4 + 2)*32 + j] = make_float4(aa2, ab2, ac2, ad2);
        P4[(kg*4 + 3)*32 + j] = make_float4(aa3, ab3, ac3, ad3);
        __syncthreads();                 // B: all partials ready

        // ---- reduce: wave r (r<4) handles row r, lanes<32; publish per row
        if (w < MB && l < 32) {
            const int rr = w;
            float4 s = P4[rr * 32 + j];
            #pragma unroll
            for (int kk = 1; kk < 16; ++kk) {
                const float4 v = P4[(kk*4 + rr)*32 + j];
                s.x += v.x; s.y += v.y; s.z += v.z; s.w += v.w;
            }
            const float xv = xall[t * MB + rr];
            s.x = tanhf(s.x + xv * wih_s[j +  0] + bias_s[j +  0]);
            s.y = tanhf(s.y + xv * wih_s[j + 32] + bias_s[j + 32]);
            s.z = tanhf(s.z + xv * wih_s[j + 64] + bias_s[j + 64]);
            s.w = tanhf(s.w + xv * wih_s[j + 96] + bias_s[j + 96]);
            float* drow = hbuf + (size_t)(p ^ 1) * BATCH * HH
                               + (size_t)(bbase + rr) * HH + jbase;
            AS(&drow[j +  0], s.x);
            AS(&drow[j + 32], s.y);
            AS(&drow[j + 64], s.z);
            AS(&drow[j + 96], s.w);
            // own-slice shortcut for waves 2*jjg, 2*jjg+1 next step
            hp[rr * HH + jbase + j +  0] = s.x;
            hp[rr * HH + jbase + j + 32] = s.y;
            hp[rr * HH + jbase + j + 64] = s.z;
            hp[rr * HH + jbase + j + 96] = s.w;
            // drain THIS wave's sc1 stores, then publish row flag
            asm volatile("s_waitcnt vmcnt(0)" ::: "memory");
            if (l == 0) AS(&wflags[bb * 16 + jjg * 4 + rr], (uint32)(t + 1));
        }
        __syncthreads();                 // C: pbuf WAR + own-slice visible
    }
}

__global__ __launch_bounds__(256) void rnn_tail_kernel(
    const float* __restrict__ hfin,   // final h in buf 0 (TT even)
    const float* __restrict__ lin_W, const float* __restrict__ lin_b,
    const int* __restrict__ y, float* __restrict__ out)
{
    __shared__ float redf[256];
    __shared__ int   redi[256];
    const int b = threadIdx.x;
    const float* hrow = hfin + (size_t)b * HH;

    float logits[NCLS];
    #pragma unroll
    for (int c = 0; c < NCLS; ++c) {
        float s = lin_b[c];
        const float* wrow = lin_W + (size_t)c * HH;
        for (int k = 0; k < HH; k += 4) {
            float4 hv = *(const float4*)(hrow + k);
            float4 wv = *(const float4*)(wrow + k);
            s += hv.x * wv.x + hv.y * wv.y + hv.z * wv.z + hv.w * wv.w;
        }
        logits[c] = s;
    }
    int am = 0; float m = logits[0];
    #pragma unroll
    for (int c = 1; c < NCLS; ++c) if (logits[c] > m) { m = logits[c]; am = c; } // first-max
    float sum = 0.0f;
    #pragma unroll
    for (int c = 0; c < NCLS; ++c) sum += expf(logits[c] - m);
    const float lse = m + logf(sum);
    const int yy = y[b];
    redf[b] = lse - logits[yy];
    redi[b] = (am == yy) ? 1 : 0;
    __syncthreads();
    for (int s2 = 128; s2 > 0; s2 >>= 1) {
        if (b < s2) { redf[b] += redf[b + s2]; redi[b] += redi[b + s2]; }
        __syncthreads();
    }
    if (b == 0) {
        out[0] = redf[0] / (float)BATCH;  // loss
        out[1] = (float)redi[0];          // correct count
    }
}

extern "C" void kernel_launch(void* const* d_in, const int* in_sizes, int n_in,
                              void* d_out, int out_size, void* d_ws, size_t ws_size,
                              hipStream_t stream) {
    const float* inputs = (const float*)d_in[0];
    const int*   y      = (const int*)  d_in[1];
    const int*   order  = (const int*)  d_in[2];
    const float* W_ih   = (const float*)d_in[3];
    const float* b_ih   = (const float*)d_in[4];
    const float* W_hh   = (const float*)d_in[5];
    const float* b_hh   = (const float*)d_in[6];
    const float* lin_W  = (const float*)d_in[7];
    const float* lin_b  = (const float*)d_in[8];
    float* out = (float*)d_out;

    uint32* wflags = (uint32*)d_ws;
    float*  hbuf   = (float*)((char*)d_ws + 8192);

    hipLaunchKernelGGL(rnn_init_kernel, dim3(4), dim3(256), 0, stream, wflags);

    void* args[] = {(void*)&inputs, (void*)&order, (void*)&W_ih, (void*)&b_ih,
                    (void*)&W_hh, (void*)&b_hh, (void*)&hbuf, (void*)&wflags};
    hipError_t err = hipLaunchCooperativeKernel((void*)rnn_main_kernel,
                                                dim3(NB * NJ), dim3(NT), args, 0, stream);
    if (err != hipSuccess) {
        hipLaunchKernelGGL(rnn_main_kernel, dim3(NB * NJ), dim3(NT), 0, stream,
                           inputs, order, W_ih, b_ih, W_hh, b_hh, hbuf, wflags);
    }

    hipLaunchKernelGGL(rnn_tail_kernel, dim3(1), dim3(256), 0, stream,
                       hbuf, lin_W, lin_b, y, out);
}